// Round 11
// baseline (3519.071 us; speedup 1.0000x reference)
//
#include <hip/hip_runtime.h>
#include <hip/hip_fp16.h>

// Problem: B=64, T=512, IN=1024, H=1024, NH=4, HD=256, NG=3
// out h: [B,T,H] then hn: [1,B,H]  (fp32)

typedef _Float16 f16x8 __attribute__((ext_vector_type(8)));
typedef _Float16 f16x4 __attribute__((ext_vector_type(4)));
typedef float    f32x4 __attribute__((ext_vector_type(4)));

#define AS1 __attribute__((address_space(1)))
#define AS3 __attribute__((address_space(3)))

__device__ __forceinline__ void async_ld16(const void* g, void* l) {
    __builtin_amdgcn_global_load_lds((const AS1 void*)g, (AS3 void*)l, 16, 0, 0);
}

__device__ __forceinline__ float sigmoidf_(float x) {
    return 1.f / (1.f + __expf(-x));
}
__device__ __forceinline__ float tanhf_(float x) {
    float e = __expf(-2.f * fabsf(x));
    float r = (1.f - e) / (1.f + e);
    return copysignf(r, x);
}

// ---- input f32 -> f16 (vectorized) ----
__global__ __launch_bounds__(256) void cast_to_f16(const float* __restrict__ in,
                                                   _Float16* __restrict__ out, int n8) {
    int i = blockIdx.x * 256 + threadIdx.x;
    if (i >= n8) return;
    const float4* p = (const float4*)in;
    float4 a = p[2 * i], b = p[2 * i + 1];
    f16x8 r;
    r[0] = (_Float16)a.x; r[1] = (_Float16)a.y; r[2] = (_Float16)a.z; r[3] = (_Float16)a.w;
    r[4] = (_Float16)b.x; r[5] = (_Float16)b.y; r[6] = (_Float16)b.z; r[7] = (_Float16)b.w;
    *(f16x8*)(out + (size_t)i * 8) = r;
}

// ---- W [1024,3072] f32 -> W^T [3072,1024] f16 ----
__global__ __launch_bounds__(256) void transpose_cast(const float* __restrict__ W,
                                                      _Float16* __restrict__ WT) {
    __shared__ float tile[32][33];
    const int tx = threadIdx.x, ty = threadIdx.y;
    const int n0 = blockIdx.x * 32, k0 = blockIdx.y * 32;
#pragma unroll
    for (int j = 0; j < 32; j += 8)
        tile[ty + j][tx] = W[(size_t)(k0 + ty + j) * 3072 + n0 + tx];
    __syncthreads();
#pragma unroll
    for (int j = 0; j < 32; j += 8)
        WT[(size_t)(n0 + ty + j) * 1024 + k0 + tx] = (_Float16)tile[tx][ty + j];
}

// ---- GEMM: WxA[t][b][gh][o] (f16) = (input @ W) + bW + bR ----
__global__ __launch_bounds__(256) void gemm_wx(const _Float16* __restrict__ A,
                                               const _Float16* __restrict__ BT,
                                               const float* __restrict__ bW,
                                               const float* __restrict__ bR,
                                               _Float16* __restrict__ WxA) {
    __shared__ _Float16 As[128 * 32];
    __shared__ _Float16 Bs[128 * 32];
    const int tid  = threadIdx.x;
    const int wave = tid >> 6, lane = tid & 63;
    const int m0 = blockIdx.y * 128, n0 = blockIdx.x * 128;
    const int wm = (wave >> 1) * 64, wn = (wave & 1) * 64;
    const int r16 = lane & 15, kq = lane >> 4;

    f32x4 acc[4][4];
#pragma unroll
    for (int m = 0; m < 4; m++)
#pragma unroll
        for (int n = 0; n < 4; n++) acc[m][n] = (f32x4){0.f, 0.f, 0.f, 0.f};

    const int srow = wave * 32 + (lane >> 2);
    const int scol = (lane & 3) * 8;

    for (int kt = 0; kt < 32; kt++) {
        const int k0 = kt * 32;
#pragma unroll
        for (int j = 0; j < 2; j++) {
            async_ld16(A  + (size_t)(m0 + srow + j * 16) * 1024 + k0 + scol,
                       As + (wave * 32 + j * 16) * 32);
            async_ld16(BT + (size_t)(n0 + srow + j * 16) * 1024 + k0 + scol,
                       Bs + (wave * 32 + j * 16) * 32);
        }
        __syncthreads();
        f16x8 af[4], bf[4];
#pragma unroll
        for (int m = 0; m < 4; m++) af[m] = *(const f16x8*)(As + (wm + m * 16 + r16) * 32 + kq * 8);
#pragma unroll
        for (int n = 0; n < 4; n++) bf[n] = *(const f16x8*)(Bs + (wn + n * 16 + r16) * 32 + kq * 8);
#pragma unroll
        for (int m = 0; m < 4; m++)
#pragma unroll
            for (int n = 0; n < 4; n++)
                acc[m][n] = __builtin_amdgcn_mfma_f32_16x16x32_f16(af[m], bf[n], acc[m][n], 0, 0, 0);
        __syncthreads();
    }

#pragma unroll
    for (int m = 0; m < 4; m++) {
        const int row0 = m0 + wm + m * 16 + (lane >> 4) * 4;
#pragma unroll
        for (int n = 0; n < 4; n++) {
            const int col  = n0 + wn + n * 16 + r16;
            const int g    = col >> 10, head = (col >> 8) & 3, o = col & 255;
            const float bias = bW[col] + bR[head * 768 + g * 256 + o];
#pragma unroll
            for (int q = 0; q < 4; q++) {
                const int rr = row0 + q;
                const int t = rr & 511, bb = rr >> 9;
                WxA[(((size_t)t * 64 + bb) * 12 + head * 3 + g) * 256 + o] =
                    (_Float16)(acc[m][n][q] + bias);
            }
        }
    }
}

// ---- repack: WxA[t][b][gh][o] f16 -> WxB[t][head][bg][o][g][b16] f16 ----
__global__ __launch_bounds__(256) void repack_wx(const _Float16* __restrict__ src,
                                                 _Float16* __restrict__ dst) {
    __shared__ _Float16 tile[16 * 768];  // [b16][g3][o256]
    const int bx = blockIdx.x;           // t*16 + head*4 + bg
    const int t = bx >> 4, head = (bx >> 2) & 3, bg = bx & 3;
    const int tid = threadIdx.x;
    {
        const int b = tid >> 4, seg = tid & 15;
        const _Float16* sp = src + (((size_t)t * 64 + bg * 16 + b) * 12 + head * 3) * 256 + seg * 48;
        _Float16* tp = tile + b * 768 + seg * 48;
#pragma unroll
        for (int u = 0; u < 6; u++)
            *(float4*)(tp + u * 8) = *(const float4*)(sp + u * 8);
    }
    __syncthreads();
    {
        const int o = tid;
        _Float16 buf[48];
#pragma unroll
        for (int g = 0; g < 3; g++)
#pragma unroll
            for (int b = 0; b < 16; b++)
                buf[g * 16 + b] = tile[b * 768 + g * 256 + o];
        _Float16* dp = dst + (size_t)bx * 12288 + o * 48;
#pragma unroll
        for (int u = 0; u < 6; u++)
            *(float4*)(dp + u * 8) = *(const float4*)(buf + u * 8);
    }
}

// ---- MFMA persistent scan: 16 blocks = (head, batch-group of 16); 256 thr = 4 waves,
// 1 wave/SIMD -> ~512-reg unified budget (m24: no spill through 450). R held as MFMA
// B-fragments (AGPR-native, zero move tax): k-tiles 0-5 in 288 regs, k-tiles 6-7
// streamed from LDS stash. Gates colocated per lane via C-layout (col=o, row=batch).
__global__ __launch_bounds__(256) void scan_mfma(const float* __restrict__ R,
                                                 const _Float16* __restrict__ Wxb,
                                                 float* __restrict__ out) {
    extern __shared__ char smem[];
    _Float16* h16 = (_Float16*)smem;                 // [2][16][266] dbuf, stride 266 (2-way banks)
    _Float16* Rst = (_Float16*)(smem + 17024);       // [3][256][74]: i in [192,256), pad 74

    const int bx = blockIdx.x;
    const int head = bx >> 2, bg = bx & 3;
    const int tid = threadIdx.x;
    const int w = tid >> 6, l = tid & 63;
    const int c = l & 15, rq = l >> 4;

    // stage Rst (k-tiles 6,7) — coalesced over o
    for (int idx = tid; idx < 3 * 64 * 256; idx += 256) {
        const int g = idx >> 14, i = (idx >> 8) & 63, o = idx & 255;
        Rst[((size_t)g * 256 + o) * 74 + i] =
            (_Float16)R[(((size_t)head * 256 + 192 + i) * 3 + g) * 256 + o];
    }
    // zero h double buffer
    for (int idx = tid; idx < 2 * 16 * 266; idx += 256) h16[idx] = (_Float16)0.f;

    // B-fragments, k-tiles 0..5: Bf[osi*3+g][kt], lane holds R[i=kt*32+rq*8+j][g][o]
    f16x8 Bf[12][6];
#pragma unroll
    for (int osi = 0; osi < 4; osi++)
#pragma unroll
        for (int g = 0; g < 3; g++) {
            const int o = (osi * 4 + w) * 16 + c;
            const float* rp = R + ((size_t)head * 256 * 3 + g) * 256 + o;
#pragma unroll
            for (int kt = 0; kt < 6; kt++) {
                f16x8 v;
#pragma unroll
                for (int j = 0; j < 8; j++)
                    v[j] = (_Float16)rp[(size_t)(kt * 32 + rq * 8 + j) * 768];
                Bf[osi * 3 + g][kt] = v;
            }
        }

    float hprev[4][4];
#pragma unroll
    for (int osi = 0; osi < 4; osi++)
#pragma unroll
        for (int q = 0; q < 4; q++) hprev[osi][q] = 0.f;

    f16x4 wx[12];
    {
        const _Float16* wp = Wxb + (size_t)bx * 12288;
#pragma unroll
        for (int osi = 0; osi < 4; osi++)
#pragma unroll
            for (int g = 0; g < 3; g++)
                wx[osi * 3 + g] = *(const f16x4*)(wp + (((osi * 4 + w) * 16 + c) * 3 + g) * 16 + rq * 4);
    }
    __syncthreads();

    int cur = 0;
    for (int t = 0; t < 512; t++) {
        const _Float16* hc = h16 + cur * (16 * 266) + c * 266 + rq * 8;
        f32x4 acc[12];
#pragma unroll
        for (int n = 0; n < 12; n++) acc[n] = (f32x4){0.f, 0.f, 0.f, 0.f};
#pragma unroll
        for (int kt = 0; kt < 6; kt++) {
            const f16x8 Af = *(const f16x8*)(hc + kt * 32);
#pragma unroll
            for (int n = 0; n < 12; n++)
                acc[n] = __builtin_amdgcn_mfma_f32_16x16x32_f16(Af, Bf[n][kt], acc[n], 0, 0, 0);
        }
#pragma unroll
        for (int kt = 6; kt < 8; kt++) {
            const f16x8 Af = *(const f16x8*)(hc + kt * 32);
#pragma unroll
            for (int osi = 0; osi < 4; osi++)
#pragma unroll
                for (int g = 0; g < 3; g++) {
                    const f16x8 Bs = *(const f16x8*)(Rst +
                        ((size_t)g * 256 + (osi * 4 + w) * 16 + c) * 74 + (kt - 6) * 32 + rq * 8);
                    acc[osi * 3 + g] =
                        __builtin_amdgcn_mfma_f32_16x16x32_f16(Af, Bs, acc[osi * 3 + g], 0, 0, 0);
                }
        }
        // gates (lane-local: col=o=lane&15 slice, rows=batch (rq*4+q))
        _Float16* hw = h16 + (cur ^ 1) * (16 * 266);
        float* outb = out + ((size_t)(bg * 16 + rq * 4) * 512 + t) * 1024 + head * 256 + w * 16 + c;
#pragma unroll
        for (int osi = 0; osi < 4; osi++) {
            const f32x4 pz = acc[osi * 3 + 0], pr = acc[osi * 3 + 1], pn = acc[osi * 3 + 2];
            const f16x4 wz = wx[osi * 3 + 0], wr = wx[osi * 3 + 1], wn = wx[osi * 3 + 2];
#pragma unroll
            for (int q = 0; q < 4; q++) {
                const float z = sigmoidf_((float)wz[q] + pz[q]);
                const float r = sigmoidf_((float)wr[q] + pr[q]);
                const float n = tanhf_((float)wn[q] + r * pn[q]);
                const float h = z * hprev[osi][q] + (1.f - z) * n;
                hprev[osi][q] = h;
                outb[(size_t)q * 512 * 1024 + osi * 64] = h;
                hw[(rq * 4 + q) * 266 + (osi * 4 + w) * 16 + c] = (_Float16)h;
            }
        }
        if (t < 511) {
            const _Float16* wp = Wxb + ((size_t)(t + 1) * 16 + bx) * 12288;
#pragma unroll
            for (int osi = 0; osi < 4; osi++)
#pragma unroll
                for (int g = 0; g < 3; g++)
                    wx[osi * 3 + g] = *(const f16x4*)(wp + (((osi * 4 + w) * 16 + c) * 3 + g) * 16 + rq * 4);
        }
        __syncthreads();
        cur ^= 1;
    }
}

// ---- hn = h[:, T-1, :] ----
__global__ __launch_bounds__(256) void copy_hn(float* __restrict__ out) {
    const int idx = blockIdx.x * 256 + threadIdx.x;  // 65536
    out[(size_t)64 * 512 * 1024 + idx] =
        out[((size_t)(idx >> 10) * 512 + 511) * 1024 + (idx & 1023)];
}

extern "C" void kernel_launch(void* const* d_in, const int* in_sizes, int n_in,
                              void* d_out, int out_size, void* d_ws, size_t ws_size,
                              hipStream_t stream) {
    (void)in_sizes; (void)n_in; (void)out_size; (void)ws_size;
    const float* inp = (const float*)d_in[0];
    const float* W   = (const float*)d_in[1];
    const float* bW  = (const float*)d_in[2];
    const float* R   = (const float*)d_in[3];
    const float* bR  = (const float*)d_in[4];
    float* out = (float*)d_out;

    // ws: A16 64MiB | WT 6MiB | WxA f16 192MiB | WxB f16 192MiB (end 476,053,504 = prior usage)
    _Float16* A16 = (_Float16*)d_ws;
    _Float16* WT  = (_Float16*)((char*)d_ws + 67108864);
    _Float16* WxA = (_Float16*)((char*)d_ws + 73400320);
    _Float16* WxB = (_Float16*)((char*)d_ws + 274726912);

    const int scan_lds = 17024 + 113664;  // 130688 B
    hipFuncSetAttribute((const void*)scan_mfma,
                        hipFuncAttributeMaxDynamicSharedMemorySize, scan_lds);

    cast_to_f16<<<16384, 256, 0, stream>>>(inp, A16, 4194304);
    transpose_cast<<<dim3(96, 32), dim3(32, 8), 0, stream>>>(W, WT);
    gemm_wx<<<dim3(24, 256), 256, 0, stream>>>(A16, WT, bW, bR, WxA);
    repack_wx<<<8192, 256, 0, stream>>>(WxA, WxB);
    scan_mfma<<<16, 256, scan_lds, stream>>>(R, WxB, out);
    copy_hn<<<256, 256, 0, stream>>>(out);
}

// Round 12
// 1057.092 us; speedup vs baseline: 3.3290x; 3.3290x over previous
//
#include <hip/hip_runtime.h>
#include <hip/hip_fp16.h>

// Problem: B=64, T=512, IN=1024, H=1024, NH=4, HD=256, NG=3
// out h: [B,T,H] then hn: [1,B,H]  (fp32)

typedef _Float16 f16x8 __attribute__((ext_vector_type(8)));
typedef float    f32x4 __attribute__((ext_vector_type(4)));

#define AS1 __attribute__((address_space(1)))
#define AS3 __attribute__((address_space(3)))

__device__ __forceinline__ void async_ld16(const void* g, void* l) {
    __builtin_amdgcn_global_load_lds((const AS1 void*)g, (AS3 void*)l, 16, 0, 0);
}

__device__ __forceinline__ float sigmoidf_(float x) {
    return 1.f / (1.f + __expf(-x));
}
__device__ __forceinline__ float tanhf_(float x) {
    float e = __expf(-2.f * fabsf(x));
    float r = (1.f - e) / (1.f + e);
    return copysignf(r, x);
}

// ---- input f32 -> f16 (vectorized) ----
__global__ __launch_bounds__(256) void cast_to_f16(const float* __restrict__ in,
                                                   _Float16* __restrict__ out, int n8) {
    int i = blockIdx.x * 256 + threadIdx.x;
    if (i >= n8) return;
    const float4* p = (const float4*)in;
    float4 a = p[2 * i], b = p[2 * i + 1];
    f16x8 r;
    r[0] = (_Float16)a.x; r[1] = (_Float16)a.y; r[2] = (_Float16)a.z; r[3] = (_Float16)a.w;
    r[4] = (_Float16)b.x; r[5] = (_Float16)b.y; r[6] = (_Float16)b.z; r[7] = (_Float16)b.w;
    *(f16x8*)(out + (size_t)i * 8) = r;
}

// ---- W [1024,3072] f32 -> W^T [3072,1024] f16 ----
__global__ __launch_bounds__(256) void transpose_cast(const float* __restrict__ W,
                                                      _Float16* __restrict__ WT) {
    __shared__ float tile[32][33];
    const int tx = threadIdx.x, ty = threadIdx.y;
    const int n0 = blockIdx.x * 32, k0 = blockIdx.y * 32;
#pragma unroll
    for (int j = 0; j < 32; j += 8)
        tile[ty + j][tx] = W[(size_t)(k0 + ty + j) * 3072 + n0 + tx];
    __syncthreads();
#pragma unroll
    for (int j = 0; j < 32; j += 8)
        WT[(size_t)(n0 + ty + j) * 1024 + k0 + tx] = (_Float16)tile[tx][ty + j];
}

// ---- GEMM: Wx[t][b][head*3+g][o] f32 = (input @ W) + bW + bR ----
__global__ __launch_bounds__(256) void gemm_wx(const _Float16* __restrict__ A,
                                               const _Float16* __restrict__ BT,
                                               const float* __restrict__ bW,
                                               const float* __restrict__ bR,
                                               float* __restrict__ Wx) {
    __shared__ _Float16 As[128 * 32];
    __shared__ _Float16 Bs[128 * 32];
    const int tid  = threadIdx.x;
    const int wave = tid >> 6, lane = tid & 63;
    const int m0 = blockIdx.y * 128, n0 = blockIdx.x * 128;
    const int wm = (wave >> 1) * 64, wn = (wave & 1) * 64;
    const int r16 = lane & 15, kq = lane >> 4;

    f32x4 acc[4][4];
#pragma unroll
    for (int m = 0; m < 4; m++)
#pragma unroll
        for (int n = 0; n < 4; n++) acc[m][n] = (f32x4){0.f, 0.f, 0.f, 0.f};

    const int srow = wave * 32 + (lane >> 2);
    const int scol = (lane & 3) * 8;

    for (int kt = 0; kt < 32; kt++) {
        const int k0 = kt * 32;
#pragma unroll
        for (int j = 0; j < 2; j++) {
            async_ld16(A  + (size_t)(m0 + srow + j * 16) * 1024 + k0 + scol,
                       As + (wave * 32 + j * 16) * 32);
            async_ld16(BT + (size_t)(n0 + srow + j * 16) * 1024 + k0 + scol,
                       Bs + (wave * 32 + j * 16) * 32);
        }
        __syncthreads();
        f16x8 af[4], bf[4];
#pragma unroll
        for (int m = 0; m < 4; m++) af[m] = *(const f16x8*)(As + (wm + m * 16 + r16) * 32 + kq * 8);
#pragma unroll
        for (int n = 0; n < 4; n++) bf[n] = *(const f16x8*)(Bs + (wn + n * 16 + r16) * 32 + kq * 8);
#pragma unroll
        for (int m = 0; m < 4; m++)
#pragma unroll
            for (int n = 0; n < 4; n++)
                acc[m][n] = __builtin_amdgcn_mfma_f32_16x16x32_f16(af[m], bf[n], acc[m][n], 0, 0, 0);
        __syncthreads();
    }

#pragma unroll
    for (int m = 0; m < 4; m++) {
        const int row0 = m0 + wm + m * 16 + (lane >> 4) * 4;
#pragma unroll
        for (int n = 0; n < 4; n++) {
            const int col  = n0 + wn + n * 16 + r16;
            const int g    = col >> 10, head = (col >> 8) & 3, o = col & 255;
            const float bias = bW[col] + bR[head * 768 + g * 256 + o];
#pragma unroll
            for (int q = 0; q < 4; q++) {
                const int rr = row0 + q;
                const int t = rr & 511, bb = rr >> 9;
                Wx[(((size_t)t * 64 + bb) * 12 + head * 3 + g) * 256 + o] = acc[m][n][q] + bias;
            }
        }
    }
}

// ---- MFMA persistent scan: 256 blocks = (b, head) = 1/CU; 512 thr = 8 waves (2/SIMD).
// Trick: broadcast h into ALL 16 A-rows -> every C row = ry (replicated) -> every lane
// holds valid (g,o) preacts in STATIC regs: no exchange, no divergence, no dynamic idx.
// Wave w owns o-slice 32 (2 o-tiles x 3 gates). B-frags (R) k-tiles 0-6 in 168 regs
// (AGPR-native for MFMA - the R2-R10 move-tax issue is structurally gone);
// k-tile 7 streamed from LDS. R staged via coalesced LDS chunks.
__global__ __launch_bounds__(512) void scan_mfma(const float* __restrict__ R,
                                                 const float* __restrict__ Wx,
                                                 float* __restrict__ out) {
    __shared__ _Float16 Rbuf[3 * 256 * 40];  // [g][o][40] pad->16B-aligned frags, 61440 B
    __shared__ _Float16 h16[2 * 256];        // h double buffer

    const int bx = blockIdx.x;
    const int head = bx >> 6, b = bx & 63;
    const int t0 = threadIdx.x;
    const int w = t0 >> 6, l = t0 & 63;
    const int c = l & 15, kq = l >> 4;
    const int o0 = w * 32;

    // ---- stage R in 8 chunks of 32 k; grab B-frags for kt 0..6; kt 7 stays in LDS ----
    f16x8 Bf[3][2][7];
#pragma unroll
    for (int kt = 0; kt < 8; kt++) {
        __syncthreads();  // protect prior chunk's reads before overwrite
        for (int idx = t0; idx < 32 * 768; idx += 512) {
            const int i2 = idx >> 8 >> 1 >> 0;        // idx / 768: do it exactly:
            const int ii = idx / 768;
            const int rem = idx - ii * 768;
            const int g = rem >> 8, o = rem & 255;
            Rbuf[(g * 256 + o) * 40 + ii] =
                (_Float16)R[(((size_t)head * 256 + kt * 32 + ii) * 3 + g) * 256 + o];
            (void)i2;
        }
        __syncthreads();
        if (kt < 7) {
#pragma unroll
            for (int g = 0; g < 3; g++)
#pragma unroll
                for (int ot = 0; ot < 2; ot++)
                    Bf[g][ot][kt] =
                        *(const f16x8*)(Rbuf + ((size_t)(g * 256 + o0 + ot * 16 + c)) * 40 + kq * 8);
        }
    }

    // init h buffers (both zero)
    if (t0 < 512) { h16[t0] = (_Float16)0.f; }
    // (2*256 == 512: one element per thread)

    float hprev[2] = {0.f, 0.f};
    float wxc[3][2];
#pragma unroll
    for (int g = 0; g < 3; g++)
#pragma unroll
        for (int o2 = 0; o2 < 2; o2++)
            wxc[g][o2] = Wx[(((size_t)0 * 64 + b) * 12 + head * 3 + g) * 256 + o0 + o2 * 16 + c];
    __syncthreads();

    float* outb = out + ((size_t)b * 512) * 1024 + head * 256;
    int cur = 0;

    for (int t = 0; t < 512; t++) {
        f32x4 acc[3][2];
#pragma unroll
        for (int g = 0; g < 3; g++)
#pragma unroll
            for (int ot = 0; ot < 2; ot++) acc[g][ot] = (f32x4){0.f, 0.f, 0.f, 0.f};

#pragma unroll
        for (int kt = 0; kt < 7; kt++) {
            const f16x8 Af = *(const f16x8*)(h16 + cur * 256 + kt * 32 + kq * 8);
#pragma unroll
            for (int g = 0; g < 3; g++)
#pragma unroll
                for (int ot = 0; ot < 2; ot++)
                    acc[g][ot] = __builtin_amdgcn_mfma_f32_16x16x32_f16(Af, Bf[g][ot][kt],
                                                                        acc[g][ot], 0, 0, 0);
        }
        {   // k-tile 7 streamed from LDS
            const f16x8 Af = *(const f16x8*)(h16 + cur * 256 + 7 * 32 + kq * 8);
#pragma unroll
            for (int g = 0; g < 3; g++)
#pragma unroll
                for (int ot = 0; ot < 2; ot++) {
                    const f16x8 Bs =
                        *(const f16x8*)(Rbuf + ((size_t)(g * 256 + o0 + ot * 16 + c)) * 40 + kq * 8);
                    acc[g][ot] = __builtin_amdgcn_mfma_f32_16x16x32_f16(Af, Bs,
                                                                        acc[g][ot], 0, 0, 0);
                }
        }

        // prefetch next wx (hidden under gate phase + barrier)
        float wxn[3][2];
        if (t < 511) {
#pragma unroll
            for (int g = 0; g < 3; g++)
#pragma unroll
                for (int o2 = 0; o2 < 2; o2++)
                    wxn[g][o2] = Wx[(((size_t)(t + 1) * 64 + b) * 12 + head * 3 + g) * 256 +
                                    o0 + o2 * 16 + c];
        } else {
            wxn[0][0] = wxn[0][1] = wxn[1][0] = wxn[1][1] = wxn[2][0] = wxn[2][1] = 0.f;
        }

        // gates: every lane computes its 2 outputs (rows replicated -> acc[..][0] valid
        // on all lanes); kq copies are redundant, only kq==0 stores.
#pragma unroll
        for (int o2 = 0; o2 < 2; o2++) {
            const float z = sigmoidf_(wxc[0][o2] + acc[0][o2][0]);
            const float r = sigmoidf_(wxc[1][o2] + acc[1][o2][0]);
            const float n = tanhf_(wxc[2][o2] + r * acc[2][o2][0]);
            const float h = z * hprev[o2] + (1.f - z) * n;
            hprev[o2] = h;
            if (kq == 0) {
                outb[(size_t)t * 1024 + o0 + o2 * 16 + c] = h;
                h16[(cur ^ 1) * 256 + o0 + o2 * 16 + c] = (_Float16)h;
            }
        }
#pragma unroll
        for (int g = 0; g < 3; g++)
#pragma unroll
            for (int o2 = 0; o2 < 2; o2++) wxc[g][o2] = wxn[g][o2];

        __syncthreads();
        cur ^= 1;
    }
}

// ---- hn = h[:, T-1, :] ----
__global__ __launch_bounds__(256) void copy_hn(float* __restrict__ out) {
    const int idx = blockIdx.x * 256 + threadIdx.x;  // 65536
    out[(size_t)64 * 512 * 1024 + idx] =
        out[((size_t)(idx >> 10) * 512 + 511) * 1024 + (idx & 1023)];
}

extern "C" void kernel_launch(void* const* d_in, const int* in_sizes, int n_in,
                              void* d_out, int out_size, void* d_ws, size_t ws_size,
                              hipStream_t stream) {
    (void)in_sizes; (void)n_in; (void)out_size; (void)ws_size;
    const float* inp = (const float*)d_in[0];
    const float* W   = (const float*)d_in[1];
    const float* bW  = (const float*)d_in[2];
    const float* R   = (const float*)d_in[3];
    const float* bR  = (const float*)d_in[4];
    float* out = (float*)d_out;

    // ws layout: A16 (64 MiB) | WT (6 MiB) | Wx f32 (384 MiB)
    _Float16* A16 = (_Float16*)d_ws;
    _Float16* WT  = (_Float16*)((char*)d_ws + 67108864);
    float*    Wx  = (float*)((char*)d_ws + 73400320);

    cast_to_f16<<<16384, 256, 0, stream>>>(inp, A16, 4194304);
    transpose_cast<<<dim3(96, 32), dim3(32, 8), 0, stream>>>(W, WT);
    gemm_wx<<<dim3(24, 256), 256, 0, stream>>>(A16, WT, bW, bR, Wx);
    scan_mfma<<<256, 512, 0, stream>>>(R, Wx, out);
    copy_hn<<<256, 256, 0, stream>>>(out);
}